// Round 2
// baseline (486.182 us; speedup 1.0000x reference)
//
#include <hip/hip_runtime.h>

#define MAXDEG 192
#define NEG_SLOPE 0.2f
#define D 128

__device__ __forceinline__ float bf2f(unsigned short u) {
    return __uint_as_float(((unsigned)u) << 16);
}
__device__ __forceinline__ unsigned short f2bf(float f) {
    unsigned u = __float_as_uint(f);
    return (unsigned short)((u + 0x7fffu + ((u >> 16) & 1u)) >> 16);
}

// ---------------------------------------------------------------------------
// 0) Runtime dtype detection. adj[0,0] == 1.0 is guaranteed (self-loop).
//    f32 world: first dword = 0x3F800000. bf16 world: 0x00003F80/0x3F803F80.
// ---------------------------------------------------------------------------
__global__ void detect_dtype(const void* __restrict__ adj, int* __restrict__ flag) {
    if (threadIdx.x == 0)
        *flag = (((const unsigned*)adj)[0] == 0x3F800000u) ? 1 : 0;
}

// ---------------------------------------------------------------------------
// 1) Build ELL adjacency: one block/row, compact nonzero column indices.
//    Order-free (softmax+sum downstream are order-independent).
// ---------------------------------------------------------------------------
__global__ __launch_bounds__(256) void build_ell(
        const void* __restrict__ adj, const int* __restrict__ flag,
        unsigned short* __restrict__ cols, int* __restrict__ deg, int N) {
    __shared__ int cnt;
    const int row = blockIdx.x;
    if (threadIdx.x == 0) cnt = 0;
    __syncthreads();
    const int f32m = *flag;
    if (f32m) {
        const float4* arow = (const float4*)((const float*)adj + (size_t)row * N);
        const int nv = N / 4;
        for (int v = threadIdx.x; v < nv; v += 256) {
            float4 u = arow[v];
            const unsigned* uu = (const unsigned*)&u;
            #pragma unroll
            for (int e = 0; e < 4; e++) {
                if (uu[e] != 0u) {
                    int p = atomicAdd(&cnt, 1);
                    if (p < MAXDEG) cols[(size_t)row * MAXDEG + p] = (unsigned short)(v * 4 + e);
                }
            }
        }
    } else {
        const uint4* arow = (const uint4*)((const unsigned short*)adj + (size_t)row * N);
        const int nv = N / 8;
        for (int v = threadIdx.x; v < nv; v += 256) {
            uint4 u = arow[v];
            const unsigned short* us = (const unsigned short*)&u;
            #pragma unroll
            for (int e = 0; e < 8; e++) {
                if (us[e] != 0) {
                    int p = atomicAdd(&cnt, 1);
                    if (p < MAXDEG) cols[(size_t)row * MAXDEG + p] = (unsigned short)(v * 8 + e);
                }
            }
        }
    }
    __syncthreads();
    if (threadIdx.x == 0) deg[row] = cnt < MAXDEG ? cnt : MAXDEG;
}

// ---------------------------------------------------------------------------
// 2) H = A(Mx128) @ W(128x128) -> f32. W staged in LDS as f32 in two 64-row
//    phases (exact in f32 world). a_force_f32: layer-1 input is f32 ws.
// ---------------------------------------------------------------------------
__global__ __launch_bounds__(256) void gemm128(
        const void* __restrict__ A, const void* __restrict__ W,
        const int* __restrict__ flag, float* __restrict__ H, int a_force_f32) {
    __shared__ float xs[32 * D];
    __shared__ float wsf[64 * D];
    const int tid = threadIdx.x;
    const size_t row0 = (size_t)blockIdx.x * 32;
    const int f32m = *flag;
    const int aF = a_force_f32 | f32m;

    if (aF) { // 32x128 f32 = 1024 float4
        const float4* av = (const float4*)((const float*)A + row0 * D);
        float4* xl = (float4*)xs;
        #pragma unroll
        for (int k = 0; k < 4; k++) xl[tid + 256 * k] = av[tid + 256 * k];
    } else {  // 32x128 bf16 = 512 uint4
        const uint4* av = (const uint4*)((const unsigned short*)A + row0 * D);
        #pragma unroll
        for (int k = 0; k < 2; k++) {
            uint4 u = av[tid + 256 * k];
            const unsigned short* us = (const unsigned short*)&u;
            #pragma unroll
            for (int e = 0; e < 8; e++) xs[(tid + 256 * k) * 8 + e] = bf2f(us[e]);
        }
    }

    const int tx = tid & 31, ty = tid >> 5;
    const int c0 = tx * 4, r0 = ty * 4;
    float acc[4][4] = {};
    for (int p = 0; p < 2; p++) {
        __syncthreads(); // previous-phase wsf reads done (also orders xs stage at p=0)
        if (f32m) {      // 64x128 f32 = 2048 float4
            const float4* wv = (const float4*)((const float*)W + (size_t)p * 64 * D);
            float4* wl = (float4*)wsf;
            #pragma unroll
            for (int k = 0; k < 8; k++) wl[tid + 256 * k] = wv[tid + 256 * k];
        } else {         // 64x128 bf16 = 1024 uint4
            const uint4* wv = (const uint4*)((const unsigned short*)W + (size_t)p * 64 * D);
            #pragma unroll
            for (int k = 0; k < 4; k++) {
                uint4 u = wv[tid + 256 * k];
                const unsigned short* us = (const unsigned short*)&u;
                #pragma unroll
                for (int e = 0; e < 8; e++) wsf[(tid + 256 * k) * 8 + e] = bf2f(us[e]);
            }
        }
        __syncthreads();
        #pragma unroll 8
        for (int k = 0; k < 64; k++) {
            float4 wv = *(const float4*)&wsf[k * D + c0];
            #pragma unroll
            for (int i = 0; i < 4; i++) {
                float xv = xs[(r0 + i) * D + p * 64 + k];
                acc[i][0] += xv * wv.x; acc[i][1] += xv * wv.y;
                acc[i][2] += xv * wv.z; acc[i][3] += xv * wv.w;
            }
        }
    }
    float* Ho = H + row0 * D;
    #pragma unroll
    for (int i = 0; i < 4; i++)
        *(float4*)&Ho[(r0 + i) * D + c0] =
            make_float4(acc[i][0], acc[i][1], acc[i][2], acc[i][3]);
}

// ---------------------------------------------------------------------------
// 3) a_src[i] = h[i].att_src ; a_dst[i] = h[i].att_dst
// ---------------------------------------------------------------------------
__global__ __launch_bounds__(128) void scores128(
        const float* __restrict__ H, const void* __restrict__ attS,
        const void* __restrict__ attD, const int* __restrict__ flag,
        float* __restrict__ asrc, float* __restrict__ adst) {
    const int i = blockIdx.x, c = threadIdx.x;
    const int f32m = *flag;
    const float as_ = f32m ? ((const float*)attS)[c] : bf2f(((const unsigned short*)attS)[c]);
    const float ad_ = f32m ? ((const float*)attD)[c] : bf2f(((const unsigned short*)attD)[c]);
    const float v = H[(size_t)i * D + c];
    float s = v * as_, d = v * ad_;
    #pragma unroll
    for (int off = 32; off > 0; off >>= 1) {
        s += __shfl_down(s, off);
        d += __shfl_down(d, off);
    }
    __shared__ float r[4];
    const int lane = c & 63, wid = c >> 6;
    if (lane == 0) { r[wid] = s; r[2 + wid] = d; }
    __syncthreads();
    if (c == 0) asrc[i] = r[0] + r[1];
    else if (c == 1) adst[i] = r[2] + r[3];
}

// ---------------------------------------------------------------------------
// 4) Per-row masked softmax + weighted aggregation + bias (+relu).
//    Writes f32 ws copy (layer-0 feeds layer-1) and the final output in the
//    detected dtype.
// ---------------------------------------------------------------------------
__global__ __launch_bounds__(256) void aggregate(
        const float* __restrict__ H,
        const float* __restrict__ asrc, const float* __restrict__ adst,
        const unsigned short* __restrict__ cols, const int* __restrict__ deg,
        const void* __restrict__ bias, const int* __restrict__ flag,
        float* __restrict__ outF, void* __restrict__ outAny,
        size_t elemOff, int relu) {
    __shared__ float sc[MAXDEG];
    __shared__ int   sj[MAXDEG];
    __shared__ float red[256];
    __shared__ float rbuf[4];
    const int i = blockIdx.x, t = threadIdx.x;
    const int d = deg[i];
    const float ai = adst[i];

    float s = -1e30f;
    if (t < d) {
        int j = cols[(size_t)i * MAXDEG + t];
        sj[t] = j;
        float e = asrc[j] + ai;
        s = (e >= 0.f) ? e : NEG_SLOPE * e;
    }
    const int lane = t & 63, wid = t >> 6;
    float m = s;
    #pragma unroll
    for (int off = 32; off > 0; off >>= 1) m = fmaxf(m, __shfl_down(m, off));
    if (lane == 0) rbuf[wid] = m;
    __syncthreads();
    m = fmaxf(fmaxf(rbuf[0], rbuf[1]), fmaxf(rbuf[2], rbuf[3]));
    float p = 0.f;
    if (t < d) { p = __expf(s - m); sc[t] = p; }
    float l = p;
    #pragma unroll
    for (int off = 32; off > 0; off >>= 1) l += __shfl_down(l, off);
    __syncthreads(); // rbuf reads done; sc[t]=p visible
    if (lane == 0) rbuf[wid] = l;
    __syncthreads();
    const float invl = 1.f / (rbuf[0] + rbuf[1] + rbuf[2] + rbuf[3]);

    // weighted gather: 2 groups of 128 threads split the neighbor list
    const int c = t & 127, g = t >> 7;
    float a0 = 0.f, a1 = 0.f;
    int k = g;
    for (; k + 2 < d; k += 4) {
        a0 += sc[k]     * H[(size_t)sj[k]     * D + c];
        a1 += sc[k + 2] * H[(size_t)sj[k + 2] * D + c];
    }
    for (; k < d; k += 2) a0 += sc[k] * H[(size_t)sj[k] * D + c];
    red[t] = a0 + a1;
    __syncthreads();
    if (g == 0) {
        const int f32m = *flag;
        const float b = f32m ? ((const float*)bias)[c] : bf2f(((const unsigned short*)bias)[c]);
        float v = (red[c] + red[128 + c]) * invl + b;
        if (relu) v = fmaxf(v, 0.f);
        if (outF) outF[(size_t)i * D + c] = v;
        if (f32m) ((float*)outAny)[elemOff + (size_t)i * D + c] = v;
        else ((unsigned short*)outAny)[elemOff + (size_t)i * D + c] = f2bf(v);
    }
}

// ---------------------------------------------------------------------------
extern "C" void kernel_launch(void* const* d_in, const int* in_sizes, int n_in,
                              void* d_out, int out_size, void* d_ws, size_t ws_size,
                              hipStream_t stream) {
    const int N = in_sizes[0] / D; // 8192

    char* w = (char*)d_ws;
    int* flag            = (int*)w;            w += 256;
    int* deg             = (int*)w;            w += (size_t)N * sizeof(int);
    unsigned short* cols = (unsigned short*)w; w += (size_t)N * MAXDEG * sizeof(unsigned short);
    float* h             = (float*)w;          w += (size_t)N * D * sizeof(float);
    float* out0          = (float*)w;          w += (size_t)N * D * sizeof(float);
    float* asrc          = (float*)w;          w += (size_t)N * sizeof(float);
    float* adst          = (float*)w;

    detect_dtype<<<1, 64, 0, stream>>>(d_in[1], flag);
    build_ell<<<N, 256, 0, stream>>>(d_in[1], flag, cols, deg, N);

    // layer 0
    gemm128<<<N / 32, 256, 0, stream>>>(d_in[0], d_in[2], flag, h, 0);
    scores128<<<N, 128, 0, stream>>>(h, d_in[3], d_in[4], flag, asrc, adst);
    aggregate<<<N, 256, 0, stream>>>(h, asrc, adst, cols, deg, d_in[5], flag,
                                     out0, d_out, 0, 1);

    // layer 1 (input = f32 out0 for accuracy)
    gemm128<<<N / 32, 256, 0, stream>>>(out0, d_in[6], flag, h, 1);
    scores128<<<N, 128, 0, stream>>>(h, d_in[7], d_in[8], flag, asrc, adst);
    aggregate<<<N, 256, 0, stream>>>(h, asrc, adst, cols, deg, d_in[9], flag,
                                     nullptr, d_out, (size_t)N * D, 0);
}

// Round 3
// 459.011 us; speedup vs baseline: 1.0592x; 1.0592x over previous
//
#include <hip/hip_runtime.h>

#define MAXDEG 192
#define NEG_SLOPE 0.2f
#define D 128

__device__ __forceinline__ float bf2f(unsigned short u) {
    return __uint_as_float(((unsigned)u) << 16);
}
__device__ __forceinline__ unsigned short f2bf(float f) {
    unsigned u = __float_as_uint(f);
    return (unsigned short)((u + 0x7fffu + ((u >> 16) & 1u)) >> 16);
}
// dtype flag derived locally: adj[0,0]==1.0 guaranteed (self-loop).
// f32 world -> first dword 0x3F800000; bf16 world -> 0x3F803F80/0x00003F80.
__device__ __forceinline__ int is_f32(const void* adj) {
    return ((const unsigned*)adj)[0] == 0x3F800000u;
}

// ---------------------------------------------------------------------------
// 1) Build ELL adjacency: one WAVE per row, 4 rows per block (2048 blocks).
//    Order-free compaction via per-wave LDS counter (compiler wave-aggregates
//    the atomicAdd).
// ---------------------------------------------------------------------------
__global__ __launch_bounds__(256) void build_ell(
        const void* __restrict__ adj,
        unsigned short* __restrict__ cols, int* __restrict__ deg, int N) {
    __shared__ int cnt[4];
    const int w = threadIdx.x >> 6, lane = threadIdx.x & 63;
    const int row = blockIdx.x * 4 + w;
    if (lane == 0) cnt[w] = 0;
    __syncthreads();
    unsigned short* crow = cols + (size_t)row * MAXDEG;
    if (is_f32(adj)) {
        const float4* arow = (const float4*)((const float*)adj + (size_t)row * N);
        const int nv = N / 4; // 2048
        for (int v = lane; v < nv; v += 128) { // 2 loads per iter in flight
            float4 u0 = arow[v];
            float4 u1 = arow[v + 64];
            const unsigned* a0 = (const unsigned*)&u0;
            const unsigned* a1 = (const unsigned*)&u1;
            #pragma unroll
            for (int e = 0; e < 4; e++)
                if (a0[e]) { int p = atomicAdd(&cnt[w], 1); if (p < MAXDEG) crow[p] = (unsigned short)(v * 4 + e); }
            #pragma unroll
            for (int e = 0; e < 4; e++)
                if (a1[e]) { int p = atomicAdd(&cnt[w], 1); if (p < MAXDEG) crow[p] = (unsigned short)((v + 64) * 4 + e); }
        }
    } else {
        const uint4* arow = (const uint4*)((const unsigned short*)adj + (size_t)row * N);
        const int nv = N / 8; // 1024
        for (int v = lane; v < nv; v += 128) {
            uint4 u0 = arow[v];
            uint4 u1 = arow[v + 64];
            const unsigned short* s0 = (const unsigned short*)&u0;
            const unsigned short* s1 = (const unsigned short*)&u1;
            #pragma unroll
            for (int e = 0; e < 8; e++)
                if (s0[e]) { int p = atomicAdd(&cnt[w], 1); if (p < MAXDEG) crow[p] = (unsigned short)(v * 8 + e); }
            #pragma unroll
            for (int e = 0; e < 8; e++)
                if (s1[e]) { int p = atomicAdd(&cnt[w], 1); if (p < MAXDEG) crow[p] = (unsigned short)((v + 64) * 8 + e); }
        }
    }
    __syncthreads();
    if (lane == 0) deg[row] = cnt[w] < MAXDEG ? cnt[w] : MAXDEG;
}

// ---------------------------------------------------------------------------
// 2) H = A(Mx128) @ W(128x128) -> f32, with fused attention scores:
//    asrc[i] = h[i].attS, adst[i] = h[i].attD  (reduced in-register).
// ---------------------------------------------------------------------------
__global__ __launch_bounds__(256) void gemm128(
        const void* __restrict__ A, const void* __restrict__ W,
        const void* __restrict__ adjFlag, float* __restrict__ H,
        const void* __restrict__ attS, const void* __restrict__ attD,
        float* __restrict__ asrc, float* __restrict__ adst, int a_force_f32) {
    __shared__ float xs[32 * D];
    __shared__ float wsf[64 * D];
    const int tid = threadIdx.x;
    const size_t row0 = (size_t)blockIdx.x * 32;
    const int f32m = is_f32(adjFlag);
    const int aF = a_force_f32 | f32m;

    if (aF) { // 32x128 f32 tile
        const float4* av = (const float4*)((const float*)A + row0 * D);
        float4* xl = (float4*)xs;
        #pragma unroll
        for (int k = 0; k < 4; k++) xl[tid + 256 * k] = av[tid + 256 * k];
    } else {  // 32x128 bf16 tile
        const uint4* av = (const uint4*)((const unsigned short*)A + row0 * D);
        #pragma unroll
        for (int k = 0; k < 2; k++) {
            uint4 u = av[tid + 256 * k];
            const unsigned short* us = (const unsigned short*)&u;
            #pragma unroll
            for (int e = 0; e < 8; e++) xs[(tid + 256 * k) * 8 + e] = bf2f(us[e]);
        }
    }

    const int tx = tid & 31, ty = tid >> 5;
    const int c0 = tx * 4, r0 = ty * 4;
    float acc[4][4] = {};
    for (int p = 0; p < 2; p++) {
        __syncthreads();
        if (f32m) {
            const float4* wv = (const float4*)((const float*)W + (size_t)p * 64 * D);
            float4* wl = (float4*)wsf;
            #pragma unroll
            for (int k = 0; k < 8; k++) wl[tid + 256 * k] = wv[tid + 256 * k];
        } else {
            const uint4* wv = (const uint4*)((const unsigned short*)W + (size_t)p * 64 * D);
            #pragma unroll
            for (int k = 0; k < 4; k++) {
                uint4 u = wv[tid + 256 * k];
                const unsigned short* us = (const unsigned short*)&u;
                #pragma unroll
                for (int e = 0; e < 8; e++) wsf[(tid + 256 * k) * 8 + e] = bf2f(us[e]);
            }
        }
        __syncthreads();
        #pragma unroll 8
        for (int k = 0; k < 64; k++) {
            float4 wv = *(const float4*)&wsf[k * D + c0];
            #pragma unroll
            for (int i = 0; i < 4; i++) {
                float xv = xs[(r0 + i) * D + p * 64 + k];
                acc[i][0] += xv * wv.x; acc[i][1] += xv * wv.y;
                acc[i][2] += xv * wv.z; acc[i][3] += xv * wv.w;
            }
        }
    }
    // store h tile
    float* Ho = H + row0 * D;
    #pragma unroll
    for (int i = 0; i < 4; i++)
        *(float4*)&Ho[(r0 + i) * D + c0] =
            make_float4(acc[i][0], acc[i][1], acc[i][2], acc[i][3]);

    // fused scores: reduce acc . att over the 32 threads sharing each row
    float aSv[4], aDv[4];
    #pragma unroll
    for (int j = 0; j < 4; j++) {
        aSv[j] = f32m ? ((const float*)attS)[c0 + j] : bf2f(((const unsigned short*)attS)[c0 + j]);
        aDv[j] = f32m ? ((const float*)attD)[c0 + j] : bf2f(((const unsigned short*)attD)[c0 + j]);
    }
    #pragma unroll
    for (int i = 0; i < 4; i++) {
        float s = acc[i][0] * aSv[0] + acc[i][1] * aSv[1] + acc[i][2] * aSv[2] + acc[i][3] * aSv[3];
        float d = acc[i][0] * aDv[0] + acc[i][1] * aDv[1] + acc[i][2] * aDv[2] + acc[i][3] * aDv[3];
        #pragma unroll
        for (int off = 16; off > 0; off >>= 1) {
            s += __shfl_down(s, off, 32);
            d += __shfl_down(d, off, 32);
        }
        if (tx == 0) {
            asrc[row0 + r0 + i] = s;
            adst[row0 + r0 + i] = d;
        }
    }
}

// ---------------------------------------------------------------------------
// 3) Per-row masked softmax + weighted aggregation + bias (+relu).
//    One WAVE per row, 4 rows per block. Softmax intra-wave (shfl_xor),
//    gather vectorized float2 with 4 independent accumulator chains.
// ---------------------------------------------------------------------------
__global__ __launch_bounds__(256) void aggregate(
        const float* __restrict__ H,
        const float* __restrict__ asrc, const float* __restrict__ adst,
        const unsigned short* __restrict__ cols, const int* __restrict__ deg,
        const void* __restrict__ bias, const void* __restrict__ adjFlag,
        float* __restrict__ outF, void* __restrict__ outAny,
        size_t elemOff, int relu) {
    __shared__ float scn[4][MAXDEG];
    __shared__ unsigned short sjj[4][MAXDEG];
    const int w = threadIdx.x >> 6, lane = threadIdx.x & 63;
    const int i = blockIdx.x * 4 + w;
    const int d = deg[i];
    const float ai = adst[i];
    const unsigned short* crow = cols + (size_t)i * MAXDEG;

    // phase A: softmax weights (3 slots per lane, wave-local reductions)
    const int s0 = lane, s1 = lane + 64, s2 = lane + 128;
    unsigned short j0 = 0, j1 = 0, j2 = 0;
    float e0 = -3e38f, e1 = -3e38f, e2 = -3e38f;
    if (s0 < d) { j0 = crow[s0]; float e = asrc[j0] + ai; e0 = (e >= 0.f) ? e : NEG_SLOPE * e; }
    if (s1 < d) { j1 = crow[s1]; float e = asrc[j1] + ai; e1 = (e >= 0.f) ? e : NEG_SLOPE * e; }
    if (s2 < d) { j2 = crow[s2]; float e = asrc[j2] + ai; e2 = (e >= 0.f) ? e : NEG_SLOPE * e; }
    float m = fmaxf(e0, fmaxf(e1, e2));
    #pragma unroll
    for (int off = 1; off < 64; off <<= 1) m = fmaxf(m, __shfl_xor(m, off));
    float p0 = (s0 < d) ? __expf(e0 - m) : 0.f;
    float p1 = (s1 < d) ? __expf(e1 - m) : 0.f;
    float p2 = (s2 < d) ? __expf(e2 - m) : 0.f;
    float l = p0 + p1 + p2;
    #pragma unroll
    for (int off = 1; off < 64; off <<= 1) l += __shfl_xor(l, off);
    const float invl = 1.f / l;
    scn[w][s0] = p0 * invl; sjj[w][s0] = j0;
    scn[w][s1] = p1 * invl; sjj[w][s1] = j1;
    scn[w][s2] = p2 * invl; sjj[w][s2] = j2;
    __syncthreads();

    // phase B: gather-weighted sum, float2 channels (c = 2*lane, 2*lane+1)
    const float2* H2 = (const float2*)H;
    float2 a0 = {0.f, 0.f}, a1 = {0.f, 0.f}, a2 = {0.f, 0.f}, a3 = {0.f, 0.f};
    int k = 0;
    for (; k + 3 < d; k += 4) {
        const int ja = sjj[w][k], jb = sjj[w][k + 1], jc = sjj[w][k + 2], jd = sjj[w][k + 3];
        const float wa = scn[w][k], wb = scn[w][k + 1], wc = scn[w][k + 2], wd = scn[w][k + 3];
        const float2 va = H2[(size_t)ja * 64 + lane];
        const float2 vb = H2[(size_t)jb * 64 + lane];
        const float2 vc = H2[(size_t)jc * 64 + lane];
        const float2 vd = H2[(size_t)jd * 64 + lane];
        a0.x += wa * va.x; a0.y += wa * va.y;
        a1.x += wb * vb.x; a1.y += wb * vb.y;
        a2.x += wc * vc.x; a2.y += wc * vc.y;
        a3.x += wd * vd.x; a3.y += wd * vd.y;
    }
    for (; k < d; k++) {
        const int j = sjj[w][k];
        const float wk = scn[w][k];
        const float2 v = H2[(size_t)j * 64 + lane];
        a0.x += wk * v.x; a0.y += wk * v.y;
    }
    float vx = a0.x + a1.x + a2.x + a3.x;
    float vy = a0.y + a1.y + a2.y + a3.y;

    const int f32m = is_f32(adjFlag);
    const int c0 = lane * 2;
    const float b0 = f32m ? ((const float*)bias)[c0]     : bf2f(((const unsigned short*)bias)[c0]);
    const float b1 = f32m ? ((const float*)bias)[c0 + 1] : bf2f(((const unsigned short*)bias)[c0 + 1]);
    vx += b0; vy += b1;
    if (relu) { vx = fmaxf(vx, 0.f); vy = fmaxf(vy, 0.f); }
    if (outF) ((float2*)outF)[(size_t)i * 64 + lane] = make_float2(vx, vy);
    if (f32m) {
        ((float2*)outAny)[(elemOff >> 1) + (size_t)i * 64 + lane] = make_float2(vx, vy);
    } else {
        unsigned packed = (unsigned)f2bf(vx) | ((unsigned)f2bf(vy) << 16);
        ((unsigned*)outAny)[(elemOff >> 1) + (size_t)i * 64 + lane] = packed;
    }
}

// ---------------------------------------------------------------------------
extern "C" void kernel_launch(void* const* d_in, const int* in_sizes, int n_in,
                              void* d_out, int out_size, void* d_ws, size_t ws_size,
                              hipStream_t stream) {
    const int N = in_sizes[0] / D; // 8192

    char* w = (char*)d_ws;
    int* deg             = (int*)w;            w += (size_t)N * sizeof(int);
    unsigned short* cols = (unsigned short*)w; w += (size_t)N * MAXDEG * sizeof(unsigned short);
    float* h             = (float*)w;          w += (size_t)N * D * sizeof(float);
    float* out0          = (float*)w;          w += (size_t)N * D * sizeof(float);
    float* asrc          = (float*)w;          w += (size_t)N * sizeof(float);
    float* adst          = (float*)w;

    const void* adj = d_in[1];

    build_ell<<<N / 4, 256, 0, stream>>>(adj, cols, deg, N);

    // layer 0
    gemm128<<<N / 32, 256, 0, stream>>>(d_in[0], d_in[2], adj, h,
                                        d_in[3], d_in[4], asrc, adst, 0);
    aggregate<<<N / 4, 256, 0, stream>>>(h, asrc, adst, cols, deg, d_in[5], adj,
                                         out0, d_out, 0, 1);

    // layer 1 (input = f32 out0 for accuracy)
    gemm128<<<N / 32, 256, 0, stream>>>(out0, d_in[6], adj, h,
                                        d_in[7], d_in[8], asrc, adst, 1);
    aggregate<<<N / 4, 256, 0, stream>>>(h, asrc, adst, cols, deg, d_in[9], adj,
                                         nullptr, d_out, (size_t)N * D, 0);
}